// Round 6
// baseline (225.829 us; speedup 1.0000x reference)
//
#include <hip/hip_runtime.h>
#include <hip/hip_bf16.h>

#define B_   8
#define N_   8192
#define S_   2048
#define D1_  128
#define D2_  256
#define CIN_ 384
#define C1_  256
#define C2_  128
#define ROWS_ (B_ * N_)   // 65536

typedef __attribute__((ext_vector_type(8))) short short8v;   // 8 bf16 (4 VGPRs)
typedef __attribute__((ext_vector_type(4))) float f32x4;     // MFMA acc

__device__ inline unsigned short f2bf(float x) {
    __hip_bfloat16 h = __float2bfloat16(x);   // RNE
    unsigned short u;
    __builtin_memcpy(&u, &h, 2);
    return u;
}
__device__ inline float bf2f(unsigned short u) {
    unsigned int x = ((unsigned int)u) << 16;
    float f;
    __builtin_memcpy(&f, &x, 4);
    return f;
}

// pack (exact f32 d, 11-bit idx) into one double: f32->f64 leaves mantissa
// bits 28..0 zero; OR idx into bits 10..0. Perturbation <= 2^-41 relative,
// strictly below f32 ULP spacing -> double order == lexicographic
// (exact f32 d, idx) == top_k's lower-index-wins tie-break. EXACT.
__device__ inline double packdi(float d, unsigned idx) {
    double dd = (double)d;
    unsigned long long u;
    __builtin_memcpy(&u, &dd, 8);
    u |= (unsigned long long)idx;
    double x;
    __builtin_memcpy(&x, &u, 8);
    return x;
}
__device__ inline unsigned unpacki(double x) {
    unsigned long long u;
    __builtin_memcpy(&u, &x, 8);
    return (unsigned)(u & 0x7FFull);
}

// branchless sorted-triple insert (e1<=e2<=e3), 3 f64 cmps + 5 selects
__device__ inline void ins3d(double x, double& e1, double& e2, double& e3) {
    bool lt1 = x < e1, lt2 = x < e2, lt3 = x < e3;
    double n3 = lt2 ? e2 : (lt3 ? x : e3);
    double n2 = lt1 ? e1 : (lt2 ? x : e2);
    double n1 = lt1 ? x : e1;
    e1 = n1; e2 = n2; e3 = n3;
}

// ---------------------------------------------------------------------------
// 3-NN, 1024 thr/block: 256 queries x 4-way S-split, exact double-packed keys.
// Distance arithmetic bit-identical to the passing round-2/3/4 versions.
// ---------------------------------------------------------------------------
__global__ __launch_bounds__(1024) void nn3_kernel(
    const float* __restrict__ xyz1, const float* __restrict__ xyz2,
    int* __restrict__ nidx, float* __restrict__ nw)
{
#pragma clang fp contract(off)
    __shared__ float4 sp[S_];                 // 32 KiB
    __shared__ double pp[4][256][3];          // 24 KiB packed partial top-3
    const int tid = threadIdx.x;
    const int b = blockIdx.y;
    const int q = tid & 255;
    const int chunk = tid >> 8;               // 0..3
    const float* x2 = xyz2 + (size_t)b * S_ * 3;
    for (int i = tid; i < S_; i += 1024) {
        float a = x2[i * 3 + 0], c = x2[i * 3 + 1], d = x2[i * 3 + 2];
        float4 v; v.x = a; v.y = c; v.z = d; v.w = (a * a + c * c) + d * d;
        sp[i] = v;
    }
    __syncthreads();
    const int n = blockIdx.x * 256 + q;
    const float* p = xyz1 + ((size_t)b * N_ + n) * 3;
    const float px = p[0], py = p[1], pz = p[2];
    const float r1 = (px * px + py * py) + pz * pz;
    double e1 = 1e300, e2 = 1e300, e3 = 1e300;
    const int s0 = chunk * 512;
#pragma unroll 4
    for (int k = 0; k < 512; ++k) {
        float4 qq = sp[s0 + k];
        float dot = (px * qq.x + py * qq.y) + pz * qq.z;
        float d = (r1 - 2.0f * dot) + qq.w;
        ins3d(packdi(d, (unsigned)(s0 | k)), e1, e2, e3);
    }
    pp[chunk][q][0] = e1; pp[chunk][q][1] = e2; pp[chunk][q][2] = e3;
    __syncthreads();
    if (tid < 256) {
        double m1 = pp[0][tid][0], m2 = pp[0][tid][1], m3 = pp[0][tid][2];
#pragma unroll
        for (int c = 1; c < 4; ++c)
#pragma unroll
            for (int e = 0; e < 3; ++e)
                ins3d(pp[c][tid][e], m1, m2, m3);
        int j1 = unpacki(m1), j2 = unpacki(m2), j3 = unpacki(m3);
        // recompute exact distances (bit-identical formula) for weights
        float4 qa = sp[j1], qb = sp[j2], qc = sp[j3];
        float da = (r1 - 2.0f * ((px * qa.x + py * qa.y) + pz * qa.z)) + qa.w;
        float db = (r1 - 2.0f * ((px * qb.x + py * qb.y) + pz * qb.z)) + qb.w;
        float dc = (r1 - 2.0f * ((px * qc.x + py * qc.y) + pz * qc.z)) + qc.w;
        float ra = 1.0f / (da + 1e-8f);
        float rb = 1.0f / (db + 1e-8f);
        float rc = 1.0f / (dc + 1e-8f);
        float sum = (ra + rb) + rc;
        size_t o = ((size_t)b * N_ + blockIdx.x * 256 + tid) * 3;
        nidx[o + 0] = j1; nidx[o + 1] = j2; nidx[o + 2] = j3;
        nw[o + 0] = ra / sum; nw[o + 1] = rb / sum; nw[o + 2] = rc / sum;
    }
}

// both weight tensors f32 -> bf16 in one launch
__global__ void cvtw_kernel(const float* __restrict__ w1, const float* __restrict__ w2,
                            unsigned short* __restrict__ w1b, unsigned short* __restrict__ w2b)
{
    int i = blockIdx.x * 256 + threadIdx.x;
    if (i < C1_ * CIN_) w1b[i] = f2bf(w1[i]);
    else {
        int j = i - C1_ * CIN_;
        if (j < C2_ * C1_) w2b[j] = f2bf(w2[j]);
    }
}

// ---------------------------------------------------------------------------
// bf16 MFMA GEMM + fused bias + fused BN-stats epilogue.
// MODE 1: A = relu(Abf[row][k]*scale[k]+shift[k]), reg-staged.
// MODE 2: A = concat(p1[row][0:128], interp(p2)[row][0:256]) built in-flight
//         (fused a1build). Each XCD handles one batch -> p2 slab L2-private.
// ---------------------------------------------------------------------------
template <int K, int COUT, int WRITE_BF16, int MODE, int GRIDCOLS>
__global__ __launch_bounds__(256) void gemm_mfma_kernel(
    const unsigned short* __restrict__ Abf,  // [ROWS][K] bf16 (MODE 1)
    const unsigned short* __restrict__ W,    // [COUT][K] bf16
    const float* __restrict__ bias,          // [COUT]
    const float* __restrict__ scale,         // [K]  (MODE 1)
    const float* __restrict__ shift,         // [K]  (MODE 1)
    const float* __restrict__ p1,            // (MODE 2)
    const float* __restrict__ p2,            // (MODE 2)
    const int* __restrict__ nidx,            // (MODE 2)
    const float* __restrict__ nw,            // (MODE 2)
    void* __restrict__ out,                  // [ROWS][COUT] bf16 or f32
    float* __restrict__ sums, float* __restrict__ ssqs)
{
    __shared__ unsigned short As[4][128][8];   // 8 KiB
    __shared__ unsigned short Bs[4][128][8];   // 8 KiB
    __shared__ float csum[128], csq[128];
    const int tid = threadIdx.x;
    const int wave = tid >> 6, lane = tid & 63;
    // XCD-chunk swizzle (grid divisible by 8): XCD x gets a contiguous chunk
    const int chunkw = (blockIdx.x & 7) * (gridDim.x >> 3) + (blockIdx.x >> 3);
    const int r0 = (chunkw / GRIDCOLS) * 128;
    const int n0 = (chunkw % GRIDCOLS) * 128;
    const int wr = wave >> 1, wc = wave & 1;
    const int kh = lane >> 4, l16 = lane & 15;

    if (tid < 128) { csum[tid] = 0.f; csq[tid] = 0.f; }

    f32x4 acc[4][4];
#pragma unroll
    for (int m = 0; m < 4; ++m)
#pragma unroll
        for (int n = 0; n < 4; ++n)
            acc[m][n] = (f32x4){0.f, 0.f, 0.f, 0.f};

    const int slotbase = wave * 64;   // wave-uniform LDS slot base

    // per-lane fixed staging metadata (2 passes -> 2 fixed rows per lane)
    int rowA[2];
    int gj0[2], gj1[2], gj2[2];
    float gw0[2], gw1[2], gw2[2];
    const float* p2b = nullptr;
    if (MODE == 2) p2b = p2 + (size_t)(r0 >> 13) * S_ * D2_;   // block-uniform batch
#pragma unroll
    for (int p = 0; p < 2; ++p) {
        const int s = p * 256 + slotbase + lane;
        rowA[p] = r0 + (s & 127);
        if (MODE == 2) {
            gj0[p] = nidx[rowA[p] * 3 + 0];
            gj1[p] = nidx[rowA[p] * 3 + 1];
            gj2[p] = nidx[rowA[p] * 3 + 2];
            gw0[p] = nw[rowA[p] * 3 + 0];
            gw1[p] = nw[rowA[p] * 3 + 1];
            gw2[p] = nw[rowA[p] * 3 + 2];
        }
    }

    for (int k0 = 0; k0 < K; k0 += 32) {
        __syncthreads();
#pragma unroll
        for (int p = 0; p < 2; ++p) {
            const int sb = p * 256 + slotbase;          // wave-uniform
            const int s = sb + lane;                    // per-lane slot
            const int kg = s >> 7, i = s & 127;
            const unsigned short* gB = W + (size_t)(n0 + i) * K + k0 + kg * 8;
            __builtin_amdgcn_global_load_lds(
                (const __attribute__((address_space(1))) void*)gB,
                (__attribute__((address_space(3))) void*)(&Bs[0][0][0] + (size_t)sb * 8),
                16, 0, 0);
            const int c0 = k0 + kg * 8;
            short8v r;
            if (MODE == 1) {
                short8v v = *(const short8v*)(Abf + (size_t)rowA[p] * K + c0);
                float4 sca = *(const float4*)(scale + c0);
                float4 scb = *(const float4*)(scale + c0 + 4);
                float4 sha = *(const float4*)(shift + c0);
                float4 shb = *(const float4*)(shift + c0 + 4);
                float sc[8] = {sca.x, sca.y, sca.z, sca.w, scb.x, scb.y, scb.z, scb.w};
                float sh[8] = {sha.x, sha.y, sha.z, sha.w, shb.x, shb.y, shb.z, shb.w};
#pragma unroll
                for (int j = 0; j < 8; ++j) {
                    float f = bf2f((unsigned short)v[j]);
                    f = fmaxf(fmaf(f, sc[j], sh[j]), 0.0f);
                    r[j] = (short)f2bf(f);
                }
            } else {
                if (k0 < D1_) {   // uniform: whole step reads points1
                    const float* q = p1 + (size_t)rowA[p] * D1_ + c0;
                    float4 a = *(const float4*)q;
                    float4 bq = *(const float4*)(q + 4);
                    float t[8] = {a.x, a.y, a.z, a.w, bq.x, bq.y, bq.z, bq.w};
#pragma unroll
                    for (int j = 0; j < 8; ++j) r[j] = (short)f2bf(t[j]);
                } else {          // uniform: whole step interpolates points2
                    const int cc = c0 - D1_;
                    const float* q0 = p2b + (size_t)gj0[p] * D2_ + cc;
                    const float* q1 = p2b + (size_t)gj1[p] * D2_ + cc;
                    const float* q2 = p2b + (size_t)gj2[p] * D2_ + cc;
                    float4 x0 = *(const float4*)q0, x0b = *(const float4*)(q0 + 4);
                    float4 x1 = *(const float4*)q1, x1b = *(const float4*)(q1 + 4);
                    float4 x2 = *(const float4*)q2, x2b = *(const float4*)(q2 + 4);
                    float a0[8] = {x0.x, x0.y, x0.z, x0.w, x0b.x, x0b.y, x0b.z, x0b.w};
                    float a1[8] = {x1.x, x1.y, x1.z, x1.w, x1b.x, x1b.y, x1b.z, x1b.w};
                    float a2[8] = {x2.x, x2.y, x2.z, x2.w, x2b.x, x2b.y, x2b.z, x2b.w};
                    const float w0 = gw0[p], w1 = gw1[p], w2 = gw2[p];
#pragma unroll
                    for (int j = 0; j < 8; ++j)
                        r[j] = (short)f2bf(a0[j] * w0 + a1[j] * w1 + a2[j] * w2);
                }
            }
            *(short8v*)&As[kg][i][0] = r;
        }
        __syncthreads();

        short8v af[4], bf[4];
#pragma unroll
        for (int m = 0; m < 4; ++m)
            af[m] = *(const short8v*)&As[kh][wr * 64 + m * 16 + l16][0];
#pragma unroll
        for (int n = 0; n < 4; ++n)
            bf[n] = *(const short8v*)&Bs[kh][wc * 64 + n * 16 + l16][0];
#pragma unroll
        for (int m = 0; m < 4; ++m)
#pragma unroll
            for (int n = 0; n < 4; ++n)
                acc[m][n] = __builtin_amdgcn_mfma_f32_16x16x32_bf16(
                    af[m], bf[n], acc[m][n], 0, 0, 0);
    }

    // epilogue: +bias, store, per-channel stats
#pragma unroll
    for (int n = 0; n < 4; ++n) {
        const int cl = wc * 64 + n * 16 + l16;       // 0..127 within tile
        const int col = n0 + cl;
        const float bv = bias[col];
        float s = 0.f, qs = 0.f;
#pragma unroll
        for (int m = 0; m < 4; ++m) {
            const int rowb = r0 + wr * 64 + m * 16 + kh * 4;
#pragma unroll
            for (int j = 0; j < 4; ++j) {
                const float v = acc[m][n][j] + bv;
                s += v; qs += v * v;
                if (WRITE_BF16)
                    ((unsigned short*)out)[(size_t)(rowb + j) * COUT + col] = f2bf(v);
                else
                    ((float*)out)[(size_t)(rowb + j) * COUT + col] = v;
            }
        }
        atomicAdd(&csum[cl], s);
        atomicAdd(&csq[cl], qs);
    }
    __syncthreads();
    if (tid < 128) {
        atomicAdd(&sums[n0 + tid], csum[tid]);
        atomicAdd(&ssqs[n0 + tid], csq[tid]);
    }
}

__global__ void finalize_kernel(const float* __restrict__ sums,
                                const float* __restrict__ ssqs,
                                const float* __restrict__ g,
                                const float* __restrict__ be,
                                float* __restrict__ scale,
                                float* __restrict__ shift, int C, float invCnt)
{
    int c = threadIdx.x;
    if (c < C) {
        float mu = sums[c] * invCnt;
        float var = ssqs[c] * invCnt - mu * mu;
        float sc = g[c] / sqrtf(var + 1e-5f);
        scale[c] = sc;
        shift[c] = be[c] - mu * sc;
    }
}

// final BN+ReLU, f32 out
__global__ __launch_bounds__(256) void bnrelu_store_kernel(
    const float* __restrict__ y, const float* __restrict__ scale,
    const float* __restrict__ shift, float* __restrict__ out)
{
    int i = blockIdx.x * 256 + threadIdx.x;   // float4 index
    float4 v = ((const float4*)y)[i];
    int o = (i * 4) & (C2_ - 1);
    float4 sc = *(const float4*)(scale + o);
    float4 sh = *(const float4*)(shift + o);
    float4 r;
    r.x = fmaxf(fmaf(v.x, sc.x, sh.x), 0.0f);
    r.y = fmaxf(fmaf(v.y, sc.y, sh.y), 0.0f);
    r.z = fmaxf(fmaf(v.z, sc.z, sh.z), 0.0f);
    r.w = fmaxf(fmaf(v.w, sc.w, sh.w), 0.0f);
    ((float4*)out)[i] = r;
}

extern "C" void kernel_launch(void* const* d_in, const int* in_sizes, int n_in,
                              void* d_out, int out_size, void* d_ws, size_t ws_size,
                              hipStream_t stream)
{
    const float* xyz1    = (const float*)d_in[0];
    const float* xyz2    = (const float*)d_in[1];
    const float* points1 = (const float*)d_in[2];
    const float* points2 = (const float*)d_in[3];
    const float* w1  = (const float*)d_in[4];
    const float* b1  = (const float*)d_in[5];
    const float* g1  = (const float*)d_in[6];
    const float* be1 = (const float*)d_in[7];
    const float* w2  = (const float*)d_in[8];
    const float* b2  = (const float*)d_in[9];
    const float* g2  = (const float*)d_in[10];
    const float* be2 = (const float*)d_in[11];
    float* out = (float*)d_out;

    char* w = (char*)d_ws;
    float*          y2  = (float*)w;                             // 33,554,432 B
    unsigned short* y1b = (unsigned short*)(w + 50331648);       // 33,554,432 B
    char* tail = w + 83886080;
    int*   nidx = (int*)tail;                                    // 786,432 B
    float* nw   = (float*)(tail + 786432);                       // 786,432 B
    unsigned short* w1b = (unsigned short*)(tail + 1572864);     // 196,608 B
    unsigned short* w2b = (unsigned short*)(tail + 1769472);     // 65,536 B
    float* sum1   = (float*)(tail + 1835008);
    float* ssq1   = sum1 + 256;
    float* sum2   = ssq1 + 256;
    float* ssq2   = sum2 + 128;
    float* scale1 = ssq2 + 128;
    float* shift1 = scale1 + 256;
    float* scale2 = shift1 + 256;
    float* shift2 = scale2 + 128;

    hipMemsetAsync(sum1, 0, (256 + 256 + 128 + 128) * sizeof(float), stream);

    cvtw_kernel<<<dim3((C1_ * CIN_ + C2_ * C1_ + 255) / 256), 256, 0, stream>>>(w1, w2, w1b, w2b);

    nn3_kernel<<<dim3(N_ / 256, B_), 1024, 0, stream>>>(xyz1, xyz2, nidx, nw);

    // GEMM1: fused concat+interp A-build, bias, BN-stats
    gemm_mfma_kernel<CIN_, C1_, 1, 2, 2><<<dim3(ROWS_ / 128 * 2), 256, 0, stream>>>(
        nullptr, w1b, b1, nullptr, nullptr, points1, points2, nidx, nw,
        (void*)y1b, sum1, ssq1);
    finalize_kernel<<<1, 256, 0, stream>>>(sum1, ssq1, g1, be1, scale1, shift1, C1_, 1.0f / ROWS_);

    // GEMM2: BN+ReLU fused on A-load, bias, BN-stats
    gemm_mfma_kernel<C1_, C2_, 0, 1, 1><<<dim3(ROWS_ / 128), 256, 0, stream>>>(
        y1b, w2b, b2, scale1, shift1, nullptr, nullptr, nullptr, nullptr,
        (void*)y2, sum2, ssq2);
    finalize_kernel<<<1, 256, 0, stream>>>(sum2, ssq2, g2, be2, scale2, shift2, C2_, 1.0f / ROWS_);

    bnrelu_store_kernel<<<dim3(ROWS_ * C2_ / 4 / 256), 256, 0, stream>>>(y2, scale2, shift2, out);
}